// Round 3
// baseline (219.533 us; speedup 1.0000x reference)
//
#include <hip/hip_runtime.h>
#include <hip/hip_bf16.h>
#include <cstdint>

typedef __bf16 bf16x8 __attribute__((ext_vector_type(8)));
typedef float f32x4 __attribute__((ext_vector_type(4)));
typedef float f32x16 __attribute__((ext_vector_type(16)));
typedef unsigned int u32;
typedef unsigned short u16;
typedef u32 u32x4 __attribute__((ext_vector_type(4)));

#define AS1 __attribute__((address_space(1)))
#define AS3 __attribute__((address_space(3)))

static __device__ __forceinline__ void gld16(const void* g, void* l) {
  __builtin_amdgcn_global_load_lds((const AS1 u32*)g, (AS3 u32*)l, 16, 0, 0);
}
static __device__ __forceinline__ u16 f2b(float f) {
  return __builtin_bit_cast(u16, __float2bfloat16(f));
}
static __device__ __forceinline__ float b2f(u16 u) {
  return __bfloat162float(__builtin_bit_cast(__hip_bfloat16, u));
}
static __device__ __forceinline__ u32 pkbf(float a, float b) {
  return (u32)f2b(a) | ((u32)f2b(b) << 16);
}

// ---------------- RoPE tables: cos/sin[t][i], t<2048, i<64 ----------------
__global__ void k_tables(float* __restrict__ cost, float* __restrict__ sint) {
  const int idx = blockIdx.x * 256 + threadIdx.x;   // 131072 total
  const int t = idx >> 6, i = idx & 63;
  const float inv = exp2f(-(float)(2 * i) * (13.287712379549449f / 128.0f));
  const float f = (float)t * inv;
  cost[idx] = cosf(f);
  sint[idx] = sinf(f);
}

// ---------------- fp32 -> bf16 convert of x, Wq, Wk, Wv ----------------
__global__ void k_convert(const float* __restrict__ x, const float* __restrict__ wq,
                          const float* __restrict__ wk, const float* __restrict__ wv,
                          u16* __restrict__ xb, u16* __restrict__ wqb,
                          u16* __restrict__ wkb, u16* __restrict__ wvb) {
  for (int i4 = blockIdx.x * blockDim.x + threadIdx.x; i4 < 3670016;
       i4 += gridDim.x * blockDim.x) {
    const int e = i4 * 4;
    const float* s; u16* d;
    if (e < 8388608)        { s = x  + e;              d = xb  + e; }
    else if (e < 12582912)  { int o = e - 8388608;  s = wq + o; d = wqb + o; }
    else if (e < 13631488)  { int o = e - 12582912; s = wk + o; d = wkb + o; }
    else                    { int o = e - 13631488; s = wv + o; d = wvb + o; }
    const float4 v = *(const float4*)s;
    ushort4 o4;
    o4.x = f2b(v.x); o4.y = f2b(v.y); o4.z = f2b(v.z); o4.w = f2b(v.w);
    *(ushort4*)d = o4;
  }
}

// ---------------- fused QKV projection GEMM (bf16 MFMA, m97 structure) ----------------
__global__ __launch_bounds__(256) void k_gemm(
    const u16* __restrict__ xb, const u16* __restrict__ wqb,
    const u16* __restrict__ wkb, const u16* __restrict__ wvb,
    u16* __restrict__ qb, u16* __restrict__ kb, u16* __restrict__ vT) {
  __shared__ __align__(16) char smA[8192];   // [128][32] bf16, source-chunk-swizzled
  __shared__ __align__(16) char smB[8192];
  const int tid = threadIdx.x;
  const int w = tid >> 6, l = tid & 63;
  const int lm = l & 15, g = l >> 4;
  const int m0 = blockIdx.x << 7;
  const int j = blockIdx.y;
  const u16* W; u16* dst; int n0, ldc, vmode;
  if (j < 16)      { W = wqb; dst = qb; n0 = j << 7;        ldc = 2048; vmode = 0; }
  else if (j < 20) { W = wkb; dst = kb; n0 = (j - 16) << 7; ldc = 512;  vmode = 0; }
  else             { W = wvb; dst = vT; n0 = (j - 20) << 7; ldc = 0;    vmode = 1; }

  const int srow = w * 16 + (l >> 2);
  const int scol = l & 3;

  f32x4 acc[4][4];
  #pragma unroll
  for (int a = 0; a < 4; ++a)
    #pragma unroll
    for (int bb = 0; bb < 4; ++bb) { f32x4 zz = {0.f, 0.f, 0.f, 0.f}; acc[a][bb] = zz; }

  const int wm = (w >> 1) << 6, wn = (w & 1) << 6;

  for (int k0 = 0; k0 < 2048; k0 += 32) {
    #pragma unroll
    for (int i = 0; i < 2; ++i) {
      const int r = srow + (i << 6);
      const int sc = (scol ^ (r & 3)) << 3;
      gld16(xb + (m0 + r) * 2048 + k0 + sc, smA + ((i * 4 + w) << 10));
      gld16(W  + (n0 + r) * 2048 + k0 + sc, smB + ((i * 4 + w) << 10));
    }
    __syncthreads();
    bf16x8 af[4], bfr[4];
    #pragma unroll
    for (int mt = 0; mt < 4; ++mt) {
      const int row = wm + mt * 16 + lm;
      af[mt] = *(const bf16x8*)(smA + row * 64 + ((g ^ (row & 3)) << 4));
    }
    #pragma unroll
    for (int nt = 0; nt < 4; ++nt) {
      const int row = wn + nt * 16 + lm;
      bfr[nt] = *(const bf16x8*)(smB + row * 64 + ((g ^ (row & 3)) << 4));
    }
    #pragma unroll
    for (int mt = 0; mt < 4; ++mt)
      #pragma unroll
      for (int nt = 0; nt < 4; ++nt)
        acc[mt][nt] = __builtin_amdgcn_mfma_f32_16x16x32_bf16(af[mt], bfr[nt], acc[mt][nt], 0, 0, 0);
    __syncthreads();
  }

  #pragma unroll
  for (int mt = 0; mt < 4; ++mt) {
    #pragma unroll
    for (int nt = 0; nt < 4; ++nt) {
      const int n = n0 + wn + nt * 16 + lm;
      #pragma unroll
      for (int r = 0; r < 4; ++r) {
        const int m = m0 + wm + mt * 16 + g * 4 + r;
        const u16 hv = f2b(acc[mt][nt][r]);
        if (!vmode) dst[m * ldc + n] = hv;
        else        dst[n * 4096 + m] = hv;
      }
    }
  }
}

// ---------------- RMSNorm + RoPE in-place on q and k ----------------
__global__ __launch_bounds__(256) void k_normrope(u16* __restrict__ qb, u16* __restrict__ kb,
                                                  const float* __restrict__ cost,
                                                  const float* __restrict__ sint) {
  const int item = blockIdx.x * 4 + (threadIdx.x >> 6);
  const int l = threadIdx.x & 63;
  u16* p; int tpos;
  if (item < 65536) { p = qb + item * 128; tpos = (item >> 4) & 2047; }
  else { const int ik = item - 65536; p = kb + ik * 128; tpos = (ik >> 2) & 2047; }
  const float f1 = b2f(p[l]);
  const float f2 = b2f(p[l + 64]);
  float ss = f1 * f1 + f2 * f2;
  #pragma unroll
  for (int d = 1; d < 64; d <<= 1) ss += __shfl_xor(ss, d);
  const float rn = rsqrtf(ss * (1.0f / 128.0f) + 1.1920928955078125e-07f);
  const float c = cost[tpos * 64 + l], s = sint[tpos * 64 + l];
  const float x1 = f1 * rn, x2 = f2 * rn;
  p[l]      = f2b(x1 * c + x2 * s);
  p[l + 64] = f2b(x2 * c - x1 * s);
}

// ---------------- causal GQA flash attention ----------------
// grid (512): block = (b, hkv) XCD-group + head-sub + tile-pair {t, 31-t} of 64 q-rows.
// 4 waves: qh = w&1 (32 q-rows), par = w>>1 (kv half of the staged 64-tile).
// Swapped form: S^T = mfma32(K, Q); O^T = mfma32(Vt, P^T). Parity merge per phase via LDS.
__global__ __launch_bounds__(256) void k_attn(
    const u16* __restrict__ qb, const u16* __restrict__ kb,
    const u16* __restrict__ vT, float* __restrict__ out) {
  __shared__ __align__(16) char lds[65536];   // [buf][K 16KB | V 16KB] x2
  __shared__ float2 smL[2][32];
  const int tid = threadIdx.x;
  const int l = tid & 63, w = tid >> 6;
  const int lq = l & 31, hi = l >> 5;
  const int qh = w & 1, par = w >> 1;

  const int bid = blockIdx.x;
  const int bb  = (bid >> 2) & 1;     // batch
  const int hkv = bid & 3;            // kv head (XCD-grouped: bid&7 = (b,hkv))
  const int wsub = bid >> 3;          // 0..63
  const int hh  = hkv * 4 + (wsub & 3);
  const int tp  = wsub >> 2;          // 0..15
  const int tA = tp, tB = 31 - tp;
  const int nA = tA + 1;              // rounds in phase A; total rounds = 33

  const u16* kbase = kb + ((size_t)bb * 2048) * 512 + hkv * 128;
  const u16* vbase = vT + ((size_t)(hkv * 128)) * 4096 + (size_t)bb * 2048;
  const u16* qhb   = qb + ((size_t)bb * 2048) * 2048 + hh * 128;

  const int krow = tid >> 4, kch = tid & 15;
  const int vrow = tid >> 3, vch = tid & 7;

  auto STAGE = [&](int buf, int jb2) {
    char* dK = lds + buf * 32768;
    char* dV = dK + 16384;
    #pragma unroll
    for (int u = 0; u < 4; ++u) {
      const int kr = u * 16 + krow;
      gld16(kbase + (size_t)(jb2 + kr) * 512 + ((kch ^ (kr & 7) ^ ((kr >> 3) & 3)) << 3),
            dK + u * 4096 + w * 1024);
      const int vr = u * 32 + vrow;
      gld16(vbase + (size_t)vr * 4096 + jb2 + ((vch ^ (vr & 7) ^ ((vr >> 3) & 3)) << 3),
            dV + u * 4096 + w * 1024);
    }
  };

  bf16x8 qf[8];
  f32x16 oacc[4], s0;
  float m = -1e30f, ll = 0.f;
  int qabs = 0, qmin = 0;
  const float cs = 1.4426950408889634f * 0.08838834764831845f;  // log2(e)/sqrt(128)

  STAGE(0, 0);
  __syncthreads();

  int cur = 0;
  for (int i = 0; i < 33; ++i) {
    const bool phB = (i >= nA);
    const int p = phB ? tB : tA;
    const int r = phB ? (i - nA) : i;
    const int nPh = phB ? (33 - nA) : nA;

    if (r == 0) {   // phase start
      qmin = p * 64 + qh * 32;
      qabs = qmin + lq;
      const u16* qp = qhb + (size_t)qabs * 2048;
      #pragma unroll
      for (int c = 0; c < 8; ++c) qf[c] = *(const bf16x8*)(qp + c * 16 + hi * 8);
      #pragma unroll
      for (int dt = 0; dt < 4; ++dt)
        #pragma unroll
        for (int e = 0; e < 16; ++e) oacc[dt][e] = 0.f;
      m = -1e30f; ll = 0.f;
    }

    if (i + 1 < 33) {
      const int jb2 = (i + 1 == nA) ? 0 : (r + 1) * 64;
      STAGE(cur ^ 1, jb2);
    }

    // ---- QK^T: S^T(32kv x 32q) for this wave's kv-parity window ----
    const char* sk = lds + cur * 32768;
    #pragma unroll
    for (int e = 0; e < 16; ++e) s0[e] = 0.f;
    __builtin_amdgcn_s_setprio(1);
    #pragma unroll
    for (int c = 0; c < 8; ++c) {
      const int ch = ((2 * c + hi) ^ (lq & 7) ^ ((lq >> 3) & 3)) << 4;
      const bf16x8 kf = *(const bf16x8*)(sk + (par * 32 + lq) * 256 + ch);
      s0 = __builtin_amdgcn_mfma_f32_32x32x16_bf16(kf, qf[c], s0, 0, 0, 0);
    }
    __builtin_amdgcn_s_setprio(0);

    // ---- online softmax over this parity's 32 kv ----
    const int jbl = r * 64 + par * 32;
    const bool diag = (jbl + 31 > qmin);
    float pmax = -3e38f;
    #pragma unroll
    for (int e2 = 0; e2 < 16; ++e2) {
      float z = s0[e2] * cs;
      if (diag) {
        const int kvl = (e2 & 3) + ((e2 >> 2) << 3) + (hi << 2);
        if (jbl + kvl > qabs) z = -1e30f;
      }
      s0[e2] = z;
      pmax = fmaxf(pmax, z);
    }
    pmax = fmaxf(pmax, __shfl_xor(pmax, 32));
    if (!__all(pmax <= m + 8.f)) {   // defer-max: rescale only on real growth
      const float mn = fmaxf(m, pmax);
      const float alpha = exp2f(m - mn);
      ll *= alpha;
      #pragma unroll
      for (int dt = 0; dt < 4; ++dt)
        #pragma unroll
        for (int e2 = 0; e2 < 16; ++e2) oacc[dt][e2] *= alpha;
      m = mn;
    }
    float rs = 0.f;
    #pragma unroll
    for (int e2 = 0; e2 < 16; ++e2) {
      const float pv = exp2f(s0[e2] - m);
      s0[e2] = pv;
      rs += pv;
    }
    rs += __shfl_xor(rs, 32);
    ll += rs;

    // ---- PV: O^T(128d x 32q) += Vt * P^T over 2 kv16-chunks ----
    const char* sv = lds + cur * 32768 + 16384;
    #pragma unroll
    for (int cc = 0; cc < 2; ++cc) {
      const int c8 = cc * 8;
      const u32 pk0 = pkbf(s0[c8 + 0], s0[c8 + 1]), pk1 = pkbf(s0[c8 + 2], s0[c8 + 3]);
      const u32 pk2 = pkbf(s0[c8 + 4], s0[c8 + 5]), pk3 = pkbf(s0[c8 + 6], s0[c8 + 7]);
      const u32 sd0 = hi ? pk0 : pk2;
      const u32 sd1 = hi ? pk1 : pk3;
      const u32 r0 = (u32)__shfl_xor((int)sd0, 32);
      const u32 r1 = (u32)__shfl_xor((int)sd1, 32);
      u32x4 bw;
      bw.x = hi ? r0 : pk0;
      bw.y = hi ? r1 : pk1;
      bw.z = hi ? pk2 : r0;
      bw.w = hi ? pk3 : r1;
      const bf16x8 pf = __builtin_bit_cast(bf16x8, bw);
      const int ch = ((4 * par + 2 * cc + hi) ^ (lq & 7) ^ ((lq >> 3) & 3)) << 4;
      __builtin_amdgcn_s_setprio(1);
      #pragma unroll
      for (int dt = 0; dt < 4; ++dt) {
        const bf16x8 vf = *(const bf16x8*)(sv + (dt * 32 + lq) * 128 + ch);
        oacc[dt] = __builtin_amdgcn_mfma_f32_32x32x16_bf16(vf, pf, oacc[dt], 0, 0, 0);
      }
      __builtin_amdgcn_s_setprio(0);
    }

    // ---- phase end: parity merge via LDS (scratch = just-consumed buffer) ----
    if (r == nPh - 1) {
      __syncthreads();
      char* scr = lds + cur * 32768 + qh * 16384;
      if (par) {
        #pragma unroll
        for (int dt = 0; dt < 4; ++dt)
          #pragma unroll
          for (int g2 = 0; g2 < 4; ++g2) {
            const int d = dt * 32 + 8 * g2 + 4 * hi;
            f32x4 v4 = { oacc[dt][g2 * 4 + 0], oacc[dt][g2 * 4 + 1],
                         oacc[dt][g2 * 4 + 2], oacc[dt][g2 * 4 + 3] };
            *(f32x4*)(scr + ((lq * 128 + (d ^ ((lq & 7) << 2))) << 2)) = v4;
          }
        if (!hi) smL[qh][lq] = make_float2(m, ll);
      }
      __syncthreads();
      if (!par) {
        const float2 ml1 = smL[qh][lq];
        const float mf = fmaxf(m, ml1.x);
        const float a0 = exp2f(m - mf), a1 = exp2f(ml1.x - mf);
        const float inv = 1.0f / (ll * a0 + ml1.y * a1);
        float* ob = out + ((size_t)(bb * 2048 + qabs)) * 2048 + hh * 128;
        #pragma unroll
        for (int dt = 0; dt < 4; ++dt)
          #pragma unroll
          for (int g2 = 0; g2 < 4; ++g2) {
            const int d = dt * 32 + 8 * g2 + 4 * hi;
            const f32x4 o1 = *(const f32x4*)(scr + ((lq * 128 + (d ^ ((lq & 7) << 2))) << 2));
            float4 w4;
            w4.x = (oacc[dt][g2 * 4 + 0] * a0 + o1[0] * a1) * inv;
            w4.y = (oacc[dt][g2 * 4 + 1] * a0 + o1[1] * a1) * inv;
            w4.z = (oacc[dt][g2 * 4 + 2] * a0 + o1[2] * a1) * inv;
            w4.w = (oacc[dt][g2 * 4 + 3] * a0 + o1[3] * a1) * inv;
            *(float4*)(ob + d) = w4;
          }
      }
    }
    __syncthreads();
    cur ^= 1;
  }
}

extern "C" void kernel_launch(void* const* d_in, const int* in_sizes, int n_in,
                              void* d_out, int out_size, void* d_ws, size_t ws_size,
                              hipStream_t stream) {
  const float* x  = (const float*)d_in[0];
  const float* wq = (const float*)d_in[1];
  const float* wk = (const float*)d_in[2];
  const float* wv = (const float*)d_in[3];
  float* out = (float*)d_out;
  char* ws = (char*)d_ws;

  float* cost = (float*)(ws);                 // 512 KB
  float* sint = (float*)(ws + 524288);        // 512 KB
  u16* xb  = (u16*)(ws + 1048576);            // 16 MB
  u16* wqb = (u16*)(ws + 17825792);           // 8 MB
  u16* wkb = (u16*)(ws + 26214400);           // 2 MB
  u16* wvb = (u16*)(ws + 28311552);           // 2 MB
  u16* qb  = (u16*)(ws + 30408704);           // 16 MB
  u16* kb  = (u16*)(ws + 47185920);           // 4 MB
  u16* vT  = (u16*)(ws + 51380224);           // 4 MB  -> total 55574528
  if (ws_size < 55574528) return;

  k_tables  <<<dim3(512),   dim3(256), 0, stream>>>(cost, sint);
  k_convert <<<dim3(2048),  dim3(256), 0, stream>>>(x, wq, wk, wv, xb, wqb, wkb, wvb);
  k_gemm    <<<dim3(32, 24), dim3(256), 0, stream>>>(xb, wqb, wkb, wvb, qb, kb, vT);
  k_normrope<<<dim3(20480), dim3(256), 0, stream>>>(qb, kb, cost, sint);
  k_attn    <<<dim3(512),   dim3(256), 0, stream>>>(qb, kb, vT, out);
}

// Round 4
// 189.733 us; speedup vs baseline: 1.1571x; 1.1571x over previous
//
#include <hip/hip_runtime.h>
#include <hip/hip_bf16.h>
#include <cstdint>

typedef __bf16 bf16x8 __attribute__((ext_vector_type(8)));
typedef float f32x4 __attribute__((ext_vector_type(4)));
typedef float f32x16 __attribute__((ext_vector_type(16)));
typedef unsigned int u32;
typedef unsigned short u16;
typedef u32 u32x4 __attribute__((ext_vector_type(4)));

#define AS1 __attribute__((address_space(1)))
#define AS3 __attribute__((address_space(3)))

static __device__ __forceinline__ void gld16(const void* g, void* l) {
  __builtin_amdgcn_global_load_lds((const AS1 u32*)g, (AS3 u32*)l, 16, 0, 0);
}
static __device__ __forceinline__ u16 f2b(float f) {
  return __builtin_bit_cast(u16, __float2bfloat16(f));
}
static __device__ __forceinline__ float b2f(u16 u) {
  return __bfloat162float(__builtin_bit_cast(__hip_bfloat16, u));
}
// one-instruction pack: lo = bf16(a), hi = bf16(b)
static __device__ __forceinline__ u32 cvtpk(float a, float b) {
  u32 r;
  asm("v_cvt_pk_bf16_f32 %0, %1, %2" : "=v"(r) : "v"(a), "v"(b));
  return r;
}

// ---------------- RoPE tables: cos/sin[t][i], t<2048, i<64 ----------------
__global__ void k_tables(float* __restrict__ cost, float* __restrict__ sint) {
  const int idx = blockIdx.x * 256 + threadIdx.x;   // 131072 total
  const int t = idx >> 6, i = idx & 63;
  const float inv = exp2f(-(float)(2 * i) * (13.287712379549449f / 128.0f));
  const float f = (float)t * inv;
  cost[idx] = cosf(f);
  sint[idx] = sinf(f);
}

// ---------------- fp32 -> bf16 convert of x, Wq, Wk, Wv ----------------
__global__ void k_convert(const float* __restrict__ x, const float* __restrict__ wq,
                          const float* __restrict__ wk, const float* __restrict__ wv,
                          u16* __restrict__ xb, u16* __restrict__ wqb,
                          u16* __restrict__ wkb, u16* __restrict__ wvb) {
  for (int i4 = blockIdx.x * blockDim.x + threadIdx.x; i4 < 3670016;
       i4 += gridDim.x * blockDim.x) {
    const int e = i4 * 4;
    const float* s; u16* d;
    if (e < 8388608)        { s = x  + e;              d = xb  + e; }
    else if (e < 12582912)  { int o = e - 8388608;  s = wq + o; d = wqb + o; }
    else if (e < 13631488)  { int o = e - 12582912; s = wk + o; d = wkb + o; }
    else                    { int o = e - 13631488; s = wv + o; d = wvb + o; }
    const float4 v = *(const float4*)s;
    ushort4 o4;
    o4.x = f2b(v.x); o4.y = f2b(v.y); o4.z = f2b(v.z); o4.w = f2b(v.w);
    *(ushort4*)d = o4;
  }
}

// ---------------- fused QKV projection GEMM (bf16 MFMA, m97 structure) ----------------
__global__ __launch_bounds__(256) void k_gemm(
    const u16* __restrict__ xb, const u16* __restrict__ wqb,
    const u16* __restrict__ wkb, const u16* __restrict__ wvb,
    u16* __restrict__ qb, u16* __restrict__ kb, u16* __restrict__ vT) {
  __shared__ __align__(16) char smA[8192];   // [128][32] bf16, source-chunk-swizzled
  __shared__ __align__(16) char smB[8192];
  const int tid = threadIdx.x;
  const int w = tid >> 6, l = tid & 63;
  const int lm = l & 15, g = l >> 4;
  const int m0 = blockIdx.x << 7;
  const int j = blockIdx.y;
  const u16* W; u16* dst; int n0, ldc, vmode;
  if (j < 16)      { W = wqb; dst = qb; n0 = j << 7;        ldc = 2048; vmode = 0; }
  else if (j < 20) { W = wkb; dst = kb; n0 = (j - 16) << 7; ldc = 512;  vmode = 0; }
  else             { W = wvb; dst = vT; n0 = (j - 20) << 7; ldc = 0;    vmode = 1; }

  const int srow = w * 16 + (l >> 2);
  const int scol = l & 3;

  f32x4 acc[4][4];
  #pragma unroll
  for (int a = 0; a < 4; ++a)
    #pragma unroll
    for (int bb = 0; bb < 4; ++bb) { f32x4 zz = {0.f, 0.f, 0.f, 0.f}; acc[a][bb] = zz; }

  const int wm = (w >> 1) << 6, wn = (w & 1) << 6;

  for (int k0 = 0; k0 < 2048; k0 += 32) {
    #pragma unroll
    for (int i = 0; i < 2; ++i) {
      const int r = srow + (i << 6);
      const int sc = (scol ^ (r & 3)) << 3;
      gld16(xb + (m0 + r) * 2048 + k0 + sc, smA + ((i * 4 + w) << 10));
      gld16(W  + (n0 + r) * 2048 + k0 + sc, smB + ((i * 4 + w) << 10));
    }
    __syncthreads();
    bf16x8 af[4], bfr[4];
    #pragma unroll
    for (int mt = 0; mt < 4; ++mt) {
      const int row = wm + mt * 16 + lm;
      af[mt] = *(const bf16x8*)(smA + row * 64 + ((g ^ (row & 3)) << 4));
    }
    #pragma unroll
    for (int nt = 0; nt < 4; ++nt) {
      const int row = wn + nt * 16 + lm;
      bfr[nt] = *(const bf16x8*)(smB + row * 64 + ((g ^ (row & 3)) << 4));
    }
    #pragma unroll
    for (int mt = 0; mt < 4; ++mt)
      #pragma unroll
      for (int nt = 0; nt < 4; ++nt)
        acc[mt][nt] = __builtin_amdgcn_mfma_f32_16x16x32_bf16(af[mt], bfr[nt], acc[mt][nt], 0, 0, 0);
    __syncthreads();
  }

  #pragma unroll
  for (int mt = 0; mt < 4; ++mt) {
    #pragma unroll
    for (int nt = 0; nt < 4; ++nt) {
      const int n = n0 + wn + nt * 16 + lm;
      #pragma unroll
      for (int r = 0; r < 4; ++r) {
        const int m = m0 + wm + mt * 16 + g * 4 + r;
        const u16 hv = f2b(acc[mt][nt][r]);
        if (!vmode) dst[m * ldc + n] = hv;
        else        dst[n * 4096 + m] = hv;
      }
    }
  }
}

// ---------------- RMSNorm + RoPE in-place on q and k ----------------
// q additionally pre-scaled by log2(e)/sqrt(128) so attention skips the scale.
__global__ __launch_bounds__(256) void k_normrope(u16* __restrict__ qb, u16* __restrict__ kb,
                                                  const float* __restrict__ cost,
                                                  const float* __restrict__ sint) {
  const int item = blockIdx.x * 4 + (threadIdx.x >> 6);
  const int l = threadIdx.x & 63;
  u16* p; int tpos; float qs;
  if (item < 65536) { p = qb + item * 128; tpos = (item >> 4) & 2047; qs = 0.12751742f; }
  else { const int ik = item - 65536; p = kb + ik * 128; tpos = (ik >> 2) & 2047; qs = 1.0f; }
  const float f1 = b2f(p[l]);
  const float f2 = b2f(p[l + 64]);
  float ss = f1 * f1 + f2 * f2;
  #pragma unroll
  for (int d = 1; d < 64; d <<= 1) ss += __shfl_xor(ss, d);
  const float rn = rsqrtf(ss * (1.0f / 128.0f) + 1.1920928955078125e-07f);
  const float c = cost[tpos * 64 + l], s = sint[tpos * 64 + l];
  const float x1 = f1 * rn, x2 = f2 * rn;
  p[l]      = f2b((x1 * c + x2 * s) * qs);
  p[l + 64] = f2b((x2 * c - x1 * s) * qs);
}

// ---------------- causal GQA flash attention, 32x32 MFMA, paired q-tiles ----------------
// grid (16, 16, 2): pair index p -> q-tiles {p, 31-p} of 64 rows; 2 waves x 32 q-rows.
// Swapped form: S^T = mfma32(K, Q) (lane owns q-col = l&31); O^T = mfma32(Vt, P^T).
__global__ __launch_bounds__(128) void k_attn(
    const u16* __restrict__ qb, const u16* __restrict__ kb,
    const u16* __restrict__ vT, float* __restrict__ out) {
  __shared__ __align__(16) char sK[2][16384];   // [64 kv][256B], chunk16 ^ (row&7)
  __shared__ __align__(16) char sV[2][16384];   // [128 d][128B], chunk16 ^ (row&7)
  const int tid = threadIdx.x;
  const int l = tid & 63;
  const int w = tid >> 6;          // wave 0/1 -> q offset 32*w
  const int lq = l & 31;
  const int hi = l >> 5;
  const int h = blockIdx.y, b = blockIdx.z;
  const int hkv = h >> 2;
  const u16* kbase = kb + ((size_t)b * 2048) * 512 + hkv * 128;
  const u16* vbase = vT + ((size_t)(hkv * 128)) * 4096 + (size_t)b * 2048;
  const u16* qhb   = qb + ((size_t)b * 2048) * 2048 + h * 128;

  const int qtA = blockIdx.x, qtB = 31 - qtA;
  const int nA = qtA + 1;
  const int total = nA + qtB + 1;   // == 33 for all blocks

  const int krow_t = tid >> 4, kch = tid & 15;
  const int vrow_t = tid >> 3, vch = tid & 7;

  bf16x8 qf[8];
  f32x16 oacc[4], s0, s1;
  float m = -1e30f, ll = 0.f;
  int qabs = 0;

  // prologue: stage kv-tile 0 into buffer 0
  #pragma unroll
  for (int u = 0; u < 8; ++u) {
    const int kr = u * 8 + krow_t;
    gld16(kbase + (size_t)kr * 512 + ((kch ^ (kr & 7)) << 3), &sK[0][u * 2048 + w * 1024]);
    const int vr = u * 16 + vrow_t;
    gld16(vbase + (size_t)vr * 4096 + ((vch ^ (vr & 7)) << 3), &sV[0][u * 2048 + w * 1024]);
  }
  __syncthreads();

  int cur = 0;
  for (int i = 0; i < total; ++i) {
    const bool phB = (i >= nA);
    const int qt = phB ? qtB : qtA;
    const int j  = phB ? (i - nA) : i;

    if (i == 0 || i == nA) {   // phase start: load Q frags, reset state
      qabs = qt * 64 + w * 32 + lq;
      const u16* qp = qhb + (size_t)qabs * 2048;
      #pragma unroll
      for (int c = 0; c < 8; ++c) qf[c] = *(const bf16x8*)(qp + c * 16 + hi * 8);
      #pragma unroll
      for (int dt = 0; dt < 4; ++dt)
        #pragma unroll
        for (int e = 0; e < 16; ++e) oacc[dt][e] = 0.f;
      m = -1e30f; ll = 0.f;
    }

    // prefetch next kv-tile into the other buffer
    if (i + 1 < total) {
      const int jb2 = (i + 1 == nA) ? 0 : (j + 1) * 64;
      char* dK = sK[cur ^ 1], * dV = sV[cur ^ 1];
      #pragma unroll
      for (int u = 0; u < 8; ++u) {
        const int kr = u * 8 + krow_t;
        gld16(kbase + (size_t)(jb2 + kr) * 512 + ((kch ^ (kr & 7)) << 3), dK + u * 2048 + w * 1024);
        const int vr = u * 16 + vrow_t;
        gld16(vbase + (size_t)vr * 4096 + jb2 + ((vch ^ (vr & 7)) << 3), dV + u * 2048 + w * 1024);
      }
    }

    // ---- QK^T: S^T(64kv x 32q) as two 32x32 subtiles ----
    #pragma unroll
    for (int e = 0; e < 16; ++e) { s0[e] = 0.f; s1[e] = 0.f; }
    const char* sk = sK[cur];
    #pragma unroll
    for (int c = 0; c < 8; ++c) {
      const int ch = ((2 * c + hi) ^ (lq & 7)) << 4;
      const bf16x8 kf0 = *(const bf16x8*)(sk + lq * 256 + ch);
      const bf16x8 kf1 = *(const bf16x8*)(sk + (32 + lq) * 256 + ch);
      s0 = __builtin_amdgcn_mfma_f32_32x32x16_bf16(kf0, qf[c], s0, 0, 0, 0);
      s1 = __builtin_amdgcn_mfma_f32_32x32x16_bf16(kf1, qf[c], s1, 0, 0, 0);
    }

    // ---- online softmax (Q pre-scaled; lane owns q-col lq; partner l^32 holds other kv) ----
    const int jb = j * 64;
    const bool diag = (j == qt);
    if (diag) {
      #pragma unroll
      for (int r = 0; r < 16; ++r) {
        const int kvl = (r & 3) + ((r >> 2) << 3) + (hi << 2);
        if (jb + kvl > qabs)      s0[r] = -1e30f;
        if (jb + 32 + kvl > qabs) s1[r] = -1e30f;
      }
    }
    // tree max (depth ~5)
    float a0[8];
    #pragma unroll
    for (int k2 = 0; k2 < 8; ++k2)
      a0[k2] = fmaxf(fmaxf(s0[2 * k2], s0[2 * k2 + 1]), fmaxf(s1[2 * k2], s1[2 * k2 + 1]));
    float pmax = fmaxf(fmaxf(fmaxf(a0[0], a0[1]), fmaxf(a0[2], a0[3])),
                       fmaxf(fmaxf(a0[4], a0[5]), fmaxf(a0[6], a0[7])));
    pmax = fmaxf(pmax, __shfl_xor(pmax, 32));
    // defer-max: rescale only on real growth (THR = 8)
    if (!__all(pmax <= m + 8.f)) {
      const float mn = fmaxf(m, pmax);
      const float alpha = exp2f(m - mn);
      ll *= alpha;
      #pragma unroll
      for (int dt = 0; dt < 4; ++dt)
        #pragma unroll
        for (int e = 0; e < 16; ++e) oacc[dt][e] *= alpha;
      m = mn;
    }
    // exp2 + tree sum (4 partials)
    float r0 = 0.f, r1 = 0.f, r2 = 0.f, r3 = 0.f;
    #pragma unroll
    for (int r = 0; r < 16; r += 4) {
      const float p00 = exp2f(s0[r] - m),     p01 = exp2f(s0[r + 1] - m);
      const float p02 = exp2f(s0[r + 2] - m), p03 = exp2f(s0[r + 3] - m);
      const float p10 = exp2f(s1[r] - m),     p11 = exp2f(s1[r + 1] - m);
      const float p12 = exp2f(s1[r + 2] - m), p13 = exp2f(s1[r + 3] - m);
      s0[r] = p00; s0[r + 1] = p01; s0[r + 2] = p02; s0[r + 3] = p03;
      s1[r] = p10; s1[r + 1] = p11; s1[r + 2] = p12; s1[r + 3] = p13;
      r0 += p00 + p01; r1 += p02 + p03; r2 += p10 + p11; r3 += p12 + p13;
    }
    float rs = (r0 + r1) + (r2 + r3);
    rs += __shfl_xor(rs, 32);
    ll += rs;

    // ---- PV: O^T(128d x 32q) += Vt * P^T over 4 kv-chunks of 16 ----
    const char* sv = sV[cur];
    #pragma unroll
    for (int cc = 0; cc < 4; ++cc) {
      const int c8 = (cc & 1) * 8;
      float q0, q1, q2, q3, q4, q5, q6, q7;
      if (cc < 2) { q0=s0[c8+0];q1=s0[c8+1];q2=s0[c8+2];q3=s0[c8+3];q4=s0[c8+4];q5=s0[c8+5];q6=s0[c8+6];q7=s0[c8+7]; }
      else        { q0=s1[c8+0];q1=s1[c8+1];q2=s1[c8+2];q3=s1[c8+3];q4=s1[c8+4];q5=s1[c8+5];q6=s1[c8+6];q7=s1[c8+7]; }
      const u32 pk0 = cvtpk(q0, q1), pk1 = cvtpk(q2, q3);
      const u32 pk2 = cvtpk(q4, q5), pk3 = cvtpk(q6, q7);
      // exchange: hi=0 sends Q1(pk2,pk3) / keeps Q0; hi=1 sends Q0(pk0,pk1) / keeps Q1
      const u32 sd0 = hi ? pk0 : pk2;
      const u32 sd1 = hi ? pk1 : pk3;
      const u32 x0 = (u32)__shfl_xor((int)sd0, 32);
      const u32 x1 = (u32)__shfl_xor((int)sd1, 32);
      u32x4 bw;
      bw.x = hi ? x0 : pk0;
      bw.y = hi ? x1 : pk1;
      bw.z = hi ? pk2 : x0;
      bw.w = hi ? pk3 : x1;
      const bf16x8 pf = __builtin_bit_cast(bf16x8, bw);
      const int ch = ((2 * cc + hi) ^ (lq & 7)) << 4;
      #pragma unroll
      for (int dt = 0; dt < 4; ++dt) {
        const bf16x8 vf = *(const bf16x8*)(sv + (dt * 32 + lq) * 128 + ch);
        oacc[dt] = __builtin_amdgcn_mfma_f32_32x32x16_bf16(vf, pf, oacc[dt], 0, 0, 0);
      }
    }

    // ---- phase end: write O ----
    if (i == nA - 1 || i == total - 1) {
      const float inv = 1.0f / ll;
      float* ob = out + ((size_t)(b * 2048 + qabs)) * 2048 + h * 128;
      #pragma unroll
      for (int dt = 0; dt < 4; ++dt)
        #pragma unroll
        for (int qd = 0; qd < 4; ++qd) {
          float4 o4;
          o4.x = oacc[dt][qd * 4 + 0] * inv;
          o4.y = oacc[dt][qd * 4 + 1] * inv;
          o4.z = oacc[dt][qd * 4 + 2] * inv;
          o4.w = oacc[dt][qd * 4 + 3] * inv;
          *(float4*)(ob + dt * 32 + qd * 8 + hi * 4) = o4;
        }
    }
    __syncthreads();
    cur ^= 1;
  }
}

extern "C" void kernel_launch(void* const* d_in, const int* in_sizes, int n_in,
                              void* d_out, int out_size, void* d_ws, size_t ws_size,
                              hipStream_t stream) {
  const float* x  = (const float*)d_in[0];
  const float* wq = (const float*)d_in[1];
  const float* wk = (const float*)d_in[2];
  const float* wv = (const float*)d_in[3];
  float* out = (float*)d_out;
  char* ws = (char*)d_ws;

  float* cost = (float*)(ws);                 // 512 KB
  float* sint = (float*)(ws + 524288);        // 512 KB
  u16* xb  = (u16*)(ws + 1048576);            // 16 MB
  u16* wqb = (u16*)(ws + 17825792);           // 8 MB
  u16* wkb = (u16*)(ws + 26214400);           // 2 MB
  u16* wvb = (u16*)(ws + 28311552);           // 2 MB
  u16* qb  = (u16*)(ws + 30408704);           // 16 MB
  u16* kb  = (u16*)(ws + 47185920);           // 4 MB
  u16* vT  = (u16*)(ws + 51380224);           // 4 MB  -> total 55574528
  if (ws_size < 55574528) return;

  k_tables  <<<dim3(512),        dim3(256), 0, stream>>>(cost, sint);
  k_convert <<<dim3(2048),       dim3(256), 0, stream>>>(x, wq, wk, wv, xb, wqb, wkb, wvb);
  k_gemm    <<<dim3(32, 24),     dim3(256), 0, stream>>>(xb, wqb, wkb, wvb, qb, kb, vT);
  k_normrope<<<dim3(20480),      dim3(256), 0, stream>>>(qb, kb, cost, sint);
  k_attn    <<<dim3(16, 16, 2),  dim3(128), 0, stream>>>(qb, kb, vT, out);
}